// Round 1
// baseline (129.877 us; speedup 1.0000x reference)
//
#include <hip/hip_runtime.h>

#define BATCH 4
#define CCH 64
#define NTOK 4096

typedef __attribute__((ext_vector_type(8))) short frag8;   // 8 bf16 (4 VGPRs)
typedef __attribute__((ext_vector_type(4))) float f32x4;   // 4 fp32 acc

static __device__ __forceinline__ unsigned short f2bf(float f) {
  union { float f; unsigned u; } v; v.f = f;
  unsigned r = v.u + 0x7FFFu + ((v.u >> 16) & 1u);   // round-to-nearest-even
  return (unsigned short)(r >> 16);
}

// ---------------------------------------------------------------------------
// Projection kernel: Q/K/V = W @ x + b per token (1x1 conv).
// Qt,Kt stored token-major [B][N][C] bf16; V channel-major [B][C][N] bf16.
// grid = B*N/64 blocks, 256 threads. Thread computes 4 outch x 4 tokens.
// ---------------------------------------------------------------------------
__global__ __launch_bounds__(256) void proj_kernel(
    const float* __restrict__ x,
    const float* __restrict__ wq, const float* __restrict__ bq,
    const float* __restrict__ wk, const float* __restrict__ bk,
    const float* __restrict__ wv, const float* __restrict__ bv,
    unsigned short* __restrict__ Qt, unsigned short* __restrict__ Kt,
    unsigned short* __restrict__ Vc)
{
  __shared__ __align__(16) float xS[64][68];        // [c][token], pad 68
  __shared__ __align__(16) float wST[3][64][68];    // [proj][c][o], pad 68
  __shared__ float bS[192];

  const int tid = threadIdx.x;
  const int blk = blockIdx.x;
  const int b  = blk >> 6;
  const int n0 = (blk & 63) * 64;

  // stage x tile: 64 c x 64 tokens fp32
  const float* xb = x + ((size_t)b * CCH) * NTOK + n0;
#pragma unroll
  for (int it = 0; it < 4; it++) {
    int ch = tid + it * 256;            // 1024 chunks of float4
    int row = ch >> 4, co = (ch & 15) * 4;
    *(float4*)&xS[row][co] = *(const float4*)(xb + (size_t)row * NTOK + co);
  }
  // stage weights transposed: wST[p][c][o] = w[p][o][c]
  for (int i = tid; i < 3 * 4096; i += 256) {
    int p = i >> 12, o = (i >> 6) & 63, cc = i & 63;
    const float* wp = (p == 0) ? wq : (p == 1) ? wk : wv;
    wST[p][cc][o] = wp[o * 64 + cc];
  }
  if (tid < 192) {
    int p = tid >> 6, o = tid & 63;
    const float* bp = (p == 0) ? bq : (p == 1) ? bk : bv;
    bS[tid] = bp[o];
  }
  __syncthreads();

  const int o0 = (tid >> 4) * 4;   // out-channel group
  const int t0 = (tid & 15) * 4;   // token group

  for (int p = 0; p < 3; p++) {
    float acc[4][4];
#pragma unroll
    for (int u = 0; u < 4; u++)
#pragma unroll
      for (int t = 0; t < 4; t++) acc[u][t] = 0.f;

#pragma unroll 8
    for (int cc = 0; cc < 64; cc++) {
      float4 w4 = *(const float4*)&wST[p][cc][o0];
      float4 x4 = *(const float4*)&xS[cc][t0];
      float wa[4] = {w4.x, w4.y, w4.z, w4.w};
      float xa[4] = {x4.x, x4.y, x4.z, x4.w};
#pragma unroll
      for (int u = 0; u < 4; u++)
#pragma unroll
        for (int t = 0; t < 4; t++)
          acc[u][t] += wa[u] * xa[t];
    }

    if (p < 2) {
      unsigned short* dst = (p == 0) ? Qt : Kt;   // [b][n][o]
#pragma unroll
      for (int t = 0; t < 4; t++) {
        ushort4 o4;
        o4.x = f2bf(acc[0][t] + bS[p * 64 + o0 + 0]);
        o4.y = f2bf(acc[1][t] + bS[p * 64 + o0 + 1]);
        o4.z = f2bf(acc[2][t] + bS[p * 64 + o0 + 2]);
        o4.w = f2bf(acc[3][t] + bS[p * 64 + o0 + 3]);
        *(ushort4*)&dst[((size_t)b * NTOK + n0 + t0 + t) * CCH + o0] = o4;
      }
    } else {
#pragma unroll
      for (int u = 0; u < 4; u++) {               // V: [b][o][n]
        float bb = bS[128 + o0 + u];
        ushort4 o4;
        o4.x = f2bf(acc[u][0] + bb);
        o4.y = f2bf(acc[u][1] + bb);
        o4.z = f2bf(acc[u][2] + bb);
        o4.w = f2bf(acc[u][3] + bb);
        *(ushort4*)&Vc[((size_t)b * CCH + o0 + u) * NTOK + n0 + t0] = o4;
      }
    }
  }
}

// ---------------------------------------------------------------------------
// Attention kernel. Block = (batch, 32 query rows), 4 waves.
// Wave w: row-tile = w>>1 (16 rows), j-half = w&1 (splits each 128-j chunk).
// No online max (logits ~1e-3 after /N scale): accumulate unnormalized O and
// rowsum (ones-B MFMA), combine wave-pair partials additively, divide once.
// MFMA layouts (measured, m89/m91/m120):
//   A[m=lane&15][k=quad*8+j], B[k=quad*8+j][n=lane&15],
//   C/D: row = quad*4+reg, col = lane&15.
// ---------------------------------------------------------------------------
__global__ __launch_bounds__(256) void attn_kernel(
    const unsigned short* __restrict__ Qt,
    const unsigned short* __restrict__ Kt,
    const unsigned short* __restrict__ Vc,
    float* __restrict__ out)
{
  __shared__ __align__(16) unsigned short KtS[128][72];   // [j][c], pad 72
  __shared__ __align__(16) unsigned short VS[64][136];    // [c][j], pad 136
  __shared__ __align__(16) unsigned short PS[4][16][72];  // per-wave P [i][j]

  const int tid  = threadIdx.x;
  const int wave = tid >> 6;
  const int lane = tid & 63;
  const int l15  = lane & 15;
  const int quad = lane >> 4;
  const int rtile = wave >> 1;   // which 16-row tile
  const int jhalf = wave & 1;    // which 64-j half of the 128-j chunk

  const int blk = blockIdx.x;
  const int b  = blk >> 7;             // 128 blocks per batch
  const int i0 = (blk & 127) * 32;

  const unsigned short* Qb = Qt + ((size_t)b * NTOK) * CCH;
  const unsigned short* Kb = Kt + ((size_t)b * NTOK) * CCH;
  const unsigned short* Vb = Vc + ((size_t)b * CCH) * NTOK;

  // Q A-fragments for this wave's 16 rows (persistent)
  frag8 qf0, qf1;
  {
    const unsigned short* qp = Qb + (size_t)(i0 + rtile * 16 + l15) * CCH;
    qf0 = *(const frag8*)(qp + quad * 8);
    qf1 = *(const frag8*)(qp + 32 + quad * 8);
  }

  f32x4 oacc[4];
#pragma unroll
  for (int i = 0; i < 4; i++) oacc[i] = (f32x4){0.f, 0.f, 0.f, 0.f};
  f32x4 rsacc = (f32x4){0.f, 0.f, 0.f, 0.f};

  frag8 ones;
#pragma unroll
  for (int i = 0; i < 8; i++) ones[i] = (short)0x3F80;    // bf16 1.0

  for (int j0 = 0; j0 < NTOK; j0 += 128) {
    __syncthreads();   // previous iteration's LDS readers done
    // --- stage Kt[j0:j0+128][0:64] and V[0:64][j0:j0+128] (bf16) ---
    {
      const uint4* src = (const uint4*)(Kb + (size_t)j0 * CCH);
#pragma unroll
      for (int it = 0; it < 4; it++) {
        int ch = tid + it * 256;               // 1024 x 16B
        int row = ch >> 3, co = (ch & 7) * 8;
        uint4 d = src[ch];
        *(uint4*)&KtS[row][co] = d;
      }
#pragma unroll
      for (int it = 0; it < 4; it++) {
        int ch = tid + it * 256;
        int row = ch >> 4, jo = (ch & 15) * 8;
        uint4 d = *(const uint4*)(Vb + (size_t)row * NTOK + j0 + jo);
        *(uint4*)&VS[row][jo] = d;
      }
    }
    __syncthreads();

    // --- GEMM1: S = Qt_i^T K_j, then P = exp(S/N) -> per-wave LDS ---
#pragma unroll
    for (int jt = 0; jt < 4; jt++) {
      int jb = jhalf * 64 + jt * 16;
      frag8 bk0 = *(const frag8*)&KtS[jb + l15][quad * 8];
      frag8 bk1 = *(const frag8*)&KtS[jb + l15][32 + quad * 8];
      f32x4 s = (f32x4){0.f, 0.f, 0.f, 0.f};
      s = __builtin_amdgcn_mfma_f32_16x16x32_bf16(qf0, bk0, s, 0, 0, 0);
      s = __builtin_amdgcn_mfma_f32_16x16x32_bf16(qf1, bk1, s, 0, 0, 0);
#pragma unroll
      for (int r = 0; r < 4; r++) {
        float p = __expf(s[r] * 2.44140625e-4f);   // 1/4096
        PS[wave][quad * 4 + r][jt * 16 + l15] = f2bf(p);
      }
    }

    // --- GEMM2: O += P * V^T ; rowsum += P * 1 (same-wave LDS round-trip) ---
#pragma unroll
    for (int kk = 0; kk < 2; kk++) {
      frag8 ap = *(const frag8*)&PS[wave][l15][kk * 32 + quad * 8];
      rsacc = __builtin_amdgcn_mfma_f32_16x16x32_bf16(ap, ones, rsacc, 0, 0, 0);
#pragma unroll
      for (int ct = 0; ct < 4; ct++) {
        frag8 bv = *(const frag8*)&VS[ct * 16 + l15][jhalf * 64 + kk * 32 + quad * 8];
        oacc[ct] = __builtin_amdgcn_mfma_f32_16x16x32_bf16(ap, bv, oacc[ct], 0, 0, 0);
      }
    }
  }

  // --- epilogue: combine j-half partials, normalize, write out[b][c][i] ---
  __syncthreads();
  float* Ored = (float*)&KtS[0][0];   // 4 waves x 16 rows x 64 c = 16 KB
  float* RS   = (float*)&VS[0][0];    // 4 waves x 16 rows
#pragma unroll
  for (int ct = 0; ct < 4; ct++)
#pragma unroll
    for (int r = 0; r < 4; r++)
      Ored[(wave * 16 + quad * 4 + r) * 64 + ct * 16 + l15] = oacc[ct][r];
  if (l15 == 0) {
#pragma unroll
    for (int r = 0; r < 4; r++)
      RS[wave * 16 + quad * 4 + r] = rsacc[r];
  }
  __syncthreads();

  const int c = tid >> 2, sgrp = tid & 3;
  float* ob = out + ((size_t)b * CCH + c) * NTOK + i0;
#pragma unroll
  for (int ii = 0; ii < 8; ii++) {
    int il = sgrp * 8 + ii;            // 0..31 local row
    int r = il >> 4, row = il & 15;    // row-tile, row within tile
    float o  = Ored[(2 * r * 16 + row) * 64 + c] +
               Ored[((2 * r + 1) * 16 + row) * 64 + c];
    float rs = RS[2 * r * 16 + row] + RS[(2 * r + 1) * 16 + row];
    ob[il] = o / rs;
  }
}

extern "C" void kernel_launch(void* const* d_in, const int* in_sizes, int n_in,
                              void* d_out, int out_size, void* d_ws, size_t ws_size,
                              hipStream_t stream) {
  const float* x  = (const float*)d_in[0];
  const float* wq = (const float*)d_in[1];
  const float* bq = (const float*)d_in[2];
  const float* wk = (const float*)d_in[3];
  const float* bk = (const float*)d_in[4];
  const float* wv = (const float*)d_in[5];
  const float* bv = (const float*)d_in[6];
  float* out = (float*)d_out;

  unsigned short* Qt = (unsigned short*)d_ws;                 // [B][N][C] bf16
  unsigned short* Kt = Qt + (size_t)BATCH * NTOK * CCH;       // [B][N][C] bf16
  unsigned short* Vc = Kt + (size_t)BATCH * NTOK * CCH;       // [B][C][N] bf16

  hipLaunchKernelGGL(proj_kernel, dim3(BATCH * NTOK / 64), dim3(256), 0, stream,
                     x, wq, bq, wk, bk, wv, bv, Qt, Kt, Vc);
  hipLaunchKernelGGL(attn_kernel, dim3(BATCH * NTOK / 32), dim3(256), 0, stream,
                     Qt, Kt, Vc, out);
}